// Round 5
// baseline (37359.192 us; speedup 1.0000x reference)
//
#include <hip/hip_runtime.h>
#include <hip/hip_bf16.h>

#define H    128
#define E    10
#define V    21
#define O    21
#define LSEQ 32768
#define G3   384            // 3*H
#define NW   (G3 + O)       // 405 worker threads: 384 gh rows + 21 decode rows

__device__ __forceinline__ float sigmoidf_(float x) { return 1.0f / (1.0f + __expf(-x)); }
__device__ __forceinline__ float tanhf_(float x)    { return 1.0f - 2.0f / (1.0f + __expf(2.0f * x)); }

// ---------------------------------------------------------------------------
// Fully fused GRU: ONE block, 512 threads (8 waves). No workspace.
//   t in [0,384)   : owns W_hh row t in regs -> gh each step        (phase A)
//   t in [384,405) : owns W_dec row (t-384) in regs -> logits(h[l-1]) (phase A)
//   t in [0,128)   : gates -> h[l]                                  (phase B)
//   t in [128,192) : log-softmax shuffle-reduce + fp32 store row l-1 (phase B)
// Output is fp32 (reference computes float32): [L*O log-softmax ; H last_h].
// ---------------------------------------------------------------------------
__global__ void __launch_bounds__(512, 1)
gru_fused(const int*   __restrict__ tokens,
          const float* __restrict__ emb,      // [V,E]
          const float* __restrict__ W_ih,     // [3H,E]
          const float* __restrict__ W_hh,     // [3H,H]
          const float* __restrict__ b_ih,     // [3H]
          const float* __restrict__ b_hh,     // [3H]
          const float* __restrict__ W_dec,    // [O,H]
          const float* __restrict__ b_dec,    // [O]
          float* __restrict__ out,            // fp32, out_size elements
          int out_size)
{
    __shared__ float X_sh[V * G3];               // per-token x-projection (21 tokens)
    __shared__ __align__(16) float h_sh[H];      // current hidden state
    __shared__ float gl_sh[NW + 3];              // [0,384): gh ; [384,405): logits

    const int t = threadIdx.x;

    // --- per-role weight row into registers (one-time) ---
    float wrow[H];
    float bias = 0.0f;
    if (t < G3) {
        #pragma unroll
        for (int k = 0; k < H; ++k) wrow[k] = W_hh[t * H + k];
        bias = b_hh[t];
    } else if (t < NW) {
        const int o = t - G3;
        #pragma unroll
        for (int k = 0; k < H; ++k) wrow[k] = W_dec[o * H + k];
        bias = b_dec[o];
    }

    // --- X_sh[v][g] = b_ih[g] + sum_e W_ih[g][e]*emb[v][e] ---
    if (t < G3) {
        float wi[E];
        #pragma unroll
        for (int e = 0; e < E; ++e) wi[e] = W_ih[t * E + e];
        const float bi = b_ih[t];
        for (int v = 0; v < V; ++v) {
            float a = bi;
            #pragma unroll
            for (int e = 0; e < E; ++e) a = fmaf(wi[e], emb[v * E + e], a);
            X_sh[v * G3 + t] = a;
        }
    }
    if (t < H) h_sh[t] = 0.0f;
    __syncthreads();

    float h_reg = 0.0f;

    for (int l = 0; l < LSEQ; ++l) {
        const int tok = tokens[l];               // wave-uniform scalar load

        // ---- phase A: gh rows [0,384) and logits(h[l-1]) rows [384,405) ----
        if (t < NW) {
            float a = bias;
            const float4* h4 = (const float4*)h_sh;
            #pragma unroll
            for (int k4 = 0; k4 < H / 4; ++k4) {
                const float4 hv = h4[k4];        // same-address LDS broadcast
                a = fmaf(wrow[4 * k4 + 0], hv.x, a);
                a = fmaf(wrow[4 * k4 + 1], hv.y, a);
                a = fmaf(wrow[4 * k4 + 2], hv.z, a);
                a = fmaf(wrow[4 * k4 + 3], hv.w, a);
            }
            gl_sh[t] = a;
        }
        __syncthreads();

        // ---- phase B: gates (t<128) + log-softmax of row l-1 (t in [128,192)) ----
        if (t < H) {
            const int base = tok * G3;
            const float r = sigmoidf_(X_sh[base + t] + gl_sh[t]);
            const float z = sigmoidf_(X_sh[base + H + t] + gl_sh[t + H]);
            const float n = tanhf_(fmaf(r, gl_sh[t + 2 * H], X_sh[base + 2 * H + t]));
            h_reg = (1.0f - z) * n + z * h_reg;
            h_sh[t] = h_reg;
        } else if (t < 192) {                    // one full wave
            const int j = t - 128;
            const float x = (j < O) ? gl_sh[G3 + j] : -3.0e38f;
            float m = x;
            #pragma unroll
            for (int d = 1; d < 64; d <<= 1) m = fmaxf(m, __shfl_xor(m, d));
            float s = __expf(x - m);
            #pragma unroll
            for (int d = 1; d < 64; d <<= 1) s += __shfl_xor(s, d);
            const float lse = m + __logf(s);
            if (l >= 1 && j < O)
                out[(size_t)(l - 1) * O + j] = x - lse;
        }
        __syncthreads();
    }

    // ---- epilogue: decode row L-1, write last_h ----
    if (t >= G3 && t < NW) {
        float a = bias;
        const float4* h4 = (const float4*)h_sh;
        #pragma unroll
        for (int k4 = 0; k4 < H / 4; ++k4) {
            const float4 hv = h4[k4];
            a = fmaf(wrow[4 * k4 + 0], hv.x, a);
            a = fmaf(wrow[4 * k4 + 1], hv.y, a);
            a = fmaf(wrow[4 * k4 + 2], hv.z, a);
            a = fmaf(wrow[4 * k4 + 3], hv.w, a);
        }
        gl_sh[t] = a;
    }
    __syncthreads();
    if (t >= 128 && t < 192) {
        const int j = t - 128;
        const float x = (j < O) ? gl_sh[G3 + j] : -3.0e38f;
        float m = x;
        #pragma unroll
        for (int d = 1; d < 64; d <<= 1) m = fmaxf(m, __shfl_xor(m, d));
        float s = __expf(x - m);
        #pragma unroll
        for (int d = 1; d < 64; d <<= 1) s += __shfl_xor(s, d);
        const float lse = m + __logf(s);
        if (j < O) out[(size_t)(LSEQ - 1) * O + j] = x - lse;
    }
    // last_hidden = final H elements of d_out
    if (t < H) out[out_size - H + t] = h_reg;
}

extern "C" void kernel_launch(void* const* d_in, const int* in_sizes, int n_in,
                              void* d_out, int out_size, void* d_ws, size_t ws_size,
                              hipStream_t stream) {
    gru_fused<<<1, 512, 0, stream>>>((const int*)d_in[0], (const float*)d_in[1],
                                     (const float*)d_in[2], (const float*)d_in[3],
                                     (const float*)d_in[4], (const float*)d_in[5],
                                     (const float*)d_in[6], (const float*)d_in[7],
                                     (float*)d_out, out_size);
}

// Round 6
// 33062.228 us; speedup vs baseline: 1.1300x; 1.1300x over previous
//
#include <hip/hip_runtime.h>
#include <hip/hip_bf16.h>

#define H    128
#define E    10
#define V    21
#define O    21
#define LSEQ 32768
#define G3   384            // 3*H

__device__ __forceinline__ float sigmoidf_(float x) { return 1.0f / (1.0f + __expf(-x)); }
__device__ __forceinline__ float tanhf_(float x)    { return 1.0f - 2.0f / (1.0f + __expf(2.0f * x)); }
__device__ __forceinline__ float bflo(unsigned u) { return __uint_as_float(u << 16); }
__device__ __forceinline__ float bfhi(unsigned u) { return __uint_as_float(u & 0xFFFF0000u); }

// ---------------------------------------------------------------------------
// GRU scan: ONE block, 768 threads (12 waves).
// Thread t owns HALF a W_hh row: row r = t>>1, k-half = t&1 -> 64 fp32 weights
// in registers (asm-pinned so LLVM cannot sink the loads into the loop — the
// round-5 failure mode: VGPR_Count=84 proved weights were re-fetched from L2
// every step, ~3200 cyc/step of L2 traffic).
// h is broadcast via LDS float4 reads (2 unique addrs/wave-instr = free).
// Gates store h_l as bf16 to global ws; decode/log-softmax is a post-pass.
// ---------------------------------------------------------------------------
__global__ void __launch_bounds__(768, 3)
gru_scan(const int*   __restrict__ tokens,
         const float* __restrict__ emb,      // [V,E]
         const float* __restrict__ W_ih,     // [3H,E]
         const float* __restrict__ W_hh,     // [3H,H]
         const float* __restrict__ b_ih,     // [3H]
         const float* __restrict__ b_hh,     // [3H]
         __hip_bfloat16* __restrict__ hiddens,  // ws [L,H] bf16
         float* __restrict__ out,            // fp32 d_out
         int out_size)
{
    __shared__ float X_sh[V * G3];               // per-token x-projection
    __shared__ __align__(16) float h_sh[H];
    __shared__ float gh_sh[G3];

    const int t  = threadIdx.x;     // 0..767
    const int r  = t >> 1;          // W_hh row 0..383
    const int kh = t & 1;           // which 64-wide k-half

    // --- 64 weights of W_hh[r, kh*64 .. kh*64+63] into registers ---
    float w[64];
    {
        const float4* src = (const float4*)(W_hh + r * H + kh * 64);
        #pragma unroll
        for (int j = 0; j < 16; ++j) {
            const float4 v = src[j];
            w[4 * j + 0] = v.x; w[4 * j + 1] = v.y;
            w[4 * j + 2] = v.z; w[4 * j + 3] = v.w;
        }
    }
    // pin: forces the 64 values live in VGPRs here; loads cannot be sunk/remat'd
    #pragma unroll
    for (int j = 0; j < 64; ++j) asm volatile("" : "+v"(w[j]));

    const float bias = (kh == 0) ? b_hh[r] : 0.0f;

    // --- X_sh[v][g] = b_ih[g] + sum_e W_ih[g][e]*emb[v][e]  (threads 0..383) ---
    if (t < G3) {
        float wi[E];
        #pragma unroll
        for (int e = 0; e < E; ++e) wi[e] = W_ih[t * E + e];
        const float bi = b_ih[t];
        for (int v = 0; v < V; ++v) {
            float a = bi;
            #pragma unroll
            for (int e = 0; e < E; ++e) a = fmaf(wi[e], emb[v * E + e], a);
            X_sh[v * G3 + t] = a;
        }
    }
    if (t < H) h_sh[t] = 0.0f;
    __syncthreads();

    float h_reg = 0.0f;

    for (int l = 0; l < LSEQ; ++l) {
        // ---- phase A: half-row dot products (all 768 threads) ----
        float a = bias;
        {
            const float4* h4 = (const float4*)h_sh + kh * 16;
            #pragma unroll
            for (int j = 0; j < 16; ++j) {
                const float4 hv = h4[j];          // broadcast (2 addrs/wave)
                a = fmaf(w[4 * j + 0], hv.x, a);
                a = fmaf(w[4 * j + 1], hv.y, a);
                a = fmaf(w[4 * j + 2], hv.z, a);
                a = fmaf(w[4 * j + 3], hv.w, a);
            }
        }
        a += __shfl_xor(a, 1);                    // combine the two halves
        if (kh == 0) gh_sh[r] = a;                // even lane writes the row
        __syncthreads();

        // ---- phase B: gates (threads 0..127) ----
        if (t < H) {
            const int base = tokens[l] * G3;      // uniform scalar load
            const float rr = sigmoidf_(X_sh[base + t]         + gh_sh[t]);
            const float zz = sigmoidf_(X_sh[base + H + t]     + gh_sh[t + H]);
            const float nn = tanhf_(fmaf(rr, gh_sh[t + 2 * H], X_sh[base + 2 * H + t]));
            h_reg = (1.0f - zz) * nn + zz * h_reg;
            h_sh[t] = h_reg;
            hiddens[(size_t)l * H + t] = __float2bfloat16(h_reg);  // fire & forget
        }
        __syncthreads();
    }

    // last_hidden = final H elements of d_out (fp32)
    if (t < H) out[out_size - H + t] = h_reg;
}

// ---------------------------------------------------------------------------
// Decode post-pass: logits = hiddens @ W_dec^T + b_dec ; log_softmax ; fp32 out.
// One sequence row per thread, 128 blocks x 256 threads. W_dec in LDS.
// ---------------------------------------------------------------------------
__global__ void __launch_bounds__(256)
gru_decode(const __hip_bfloat16* __restrict__ hiddens, // [L,H] bf16
           const float* __restrict__ W_dec,            // [O,H]
           const float* __restrict__ b_dec,            // [O]
           float* __restrict__ out)                    // [L,O] fp32
{
    __shared__ float wd[O * H];
    __shared__ float bd[O];
    const int t = threadIdx.x;
    for (int i = t; i < O * H; i += 256) wd[i] = W_dec[i];
    if (t < O) bd[t] = b_dec[t];
    __syncthreads();

    const int row = blockIdx.x * 256 + t;    // grid = L/256
    float logit[O];
    #pragma unroll
    for (int o = 0; o < O; ++o) logit[o] = bd[o];

    const uint4* hp = (const uint4*)(hiddens + (size_t)row * H);
    #pragma unroll
    for (int j = 0; j < H / 8; ++j) {
        const uint4 u = hp[j];
        const float h0 = bflo(u.x), h1 = bfhi(u.x);
        const float h2 = bflo(u.y), h3 = bfhi(u.y);
        const float h4 = bflo(u.z), h5 = bfhi(u.z);
        const float h6 = bflo(u.w), h7 = bfhi(u.w);
        const int c = j * 8;
        #pragma unroll
        for (int o = 0; o < O; ++o) {
            const float* wr = wd + o * H + c;    // uniform addr -> broadcast
            float a = logit[o];
            a = fmaf(wr[0], h0, a); a = fmaf(wr[1], h1, a);
            a = fmaf(wr[2], h2, a); a = fmaf(wr[3], h3, a);
            a = fmaf(wr[4], h4, a); a = fmaf(wr[5], h5, a);
            a = fmaf(wr[6], h6, a); a = fmaf(wr[7], h7, a);
            logit[o] = a;
        }
    }

    float m = logit[0];
    #pragma unroll
    for (int o = 1; o < O; ++o) m = fmaxf(m, logit[o]);
    float s = 0.0f;
    #pragma unroll
    for (int o = 0; o < O; ++o) s += __expf(logit[o] - m);
    const float lse = m + __logf(s);
    #pragma unroll
    for (int o = 0; o < O; ++o)
        out[(size_t)row * O + o] = logit[o] - lse;
}

extern "C" void kernel_launch(void* const* d_in, const int* in_sizes, int n_in,
                              void* d_out, int out_size, void* d_ws, size_t ws_size,
                              hipStream_t stream) {
    const int*   tokens = (const int*)d_in[0];
    const float* emb    = (const float*)d_in[1];
    const float* W_ih   = (const float*)d_in[2];
    const float* W_hh   = (const float*)d_in[3];
    const float* b_ih   = (const float*)d_in[4];
    const float* b_hh   = (const float*)d_in[5];
    const float* W_dec  = (const float*)d_in[6];
    const float* b_dec  = (const float*)d_in[7];
    float* out = (float*)d_out;
    __hip_bfloat16* hiddens = (__hip_bfloat16*)d_ws;   // L*H*2 = 8.4 MB

    gru_scan<<<1, 768, 0, stream>>>(tokens, emb, W_ih, W_hh, b_ih, b_hh,
                                    hiddens, out, out_size);
    gru_decode<<<LSEQ / 256, 256, 0, stream>>>(hiddens, W_dec, b_dec, out);
}

// Round 7
// 17106.503 us; speedup vs baseline: 2.1839x; 1.9327x over previous
//
#include <hip/hip_runtime.h>
#include <hip/hip_bf16.h>
#include <string.h>

#define H    128
#define E    10
#define V    21
#define O    21
#define LSEQ 32768
#define G3   384            // 3*H

typedef __attribute__((ext_vector_type(8))) short bf16x8;   // 8 bf16 = 4 VGPRs
typedef __attribute__((ext_vector_type(4))) float f32x4;

__device__ __forceinline__ float sigmoidf_(float x) { return 1.0f / (1.0f + __expf(-x)); }
__device__ __forceinline__ float tanhf_(float x)    { return 1.0f - 2.0f / (1.0f + __expf(2.0f * x)); }
__device__ __forceinline__ float bflo(unsigned u) { return __uint_as_float(u << 16); }
__device__ __forceinline__ float bfhi(unsigned u) { return __uint_as_float(u & 0xFFFF0000u); }

__device__ __forceinline__ short f2bf(float f) {
    __hip_bfloat16 h = __float2bfloat16(f);     // RNE
    return __builtin_bit_cast(short, h);
}

// ---------------------------------------------------------------------------
// GRU scan via MFMA: ONE block, 512 threads (8 waves).
// gh = W_hh·h + b_hh computed as 24 (16-row) tiles x 4 (32-k) tiles of
// v_mfma_f32_16x16x32_bf16. Wave w owns row-tiles 3w..3w+2: 12 A-fragments
// (48 VGPRs) resident across the whole scan; b_hh folded into the acc init.
// h is replicated into all 16 B columns (every D column identical -> layout-
// permutation-proof; only the k-mapping k=quad*8+j matters).
// amdgpu_waves_per_eu(2,2): pins backend occupancy target to our actual
// 2 waves/SIMD -> 256-VGPR budget, defeating the R5/R6 pressure-shrink
// heuristic that spilled/sank the weights (R6: VGPR_Count=48 for 64 weights).
// ---------------------------------------------------------------------------
__global__ void __launch_bounds__(512)
__attribute__((amdgpu_waves_per_eu(2, 2)))
gru_scan(const int*   __restrict__ tokens,
         const float* __restrict__ emb,      // [V,E]
         const float* __restrict__ W_ih,     // [3H,E]
         const float* __restrict__ W_hh,     // [3H,H]
         const float* __restrict__ b_ih,     // [3H]
         const float* __restrict__ b_hh,     // [3H]
         __hip_bfloat16* __restrict__ hiddens,  // ws [L,H] bf16
         float* __restrict__ out,            // fp32 d_out
         int out_size)
{
    __shared__ float X_sh[V * G3];                    // per-token xp (incl. b_ih)
    __shared__ float gh_sh[G3];                       // W_hh·h + b_hh
    __shared__ __align__(16) short hbf_sh[H];         // h in bf16 for MFMA B

    const int t    = threadIdx.x;     // 0..511
    const int w    = t >> 6;          // wave 0..7
    const int lane = t & 63;
    const int quad = lane >> 4;       // 0..3
    const int col  = lane & 15;       // MFMA m / n / col index

    // --- A-fragments: W_hh rows for tiles rt=3w..3w+2, bf16, resident ---
    // A[m][k]: m = lane&15 (row within tile), k = quad*8 + j  (j=0..7)
    bf16x8 afrag[3][4];
    f32x4  biasf[3];
    #pragma unroll
    for (int i = 0; i < 3; ++i) {
        const int rt  = 3 * w + i;
        const int row = rt * 16 + col;
        #pragma unroll
        for (int kt = 0; kt < 4; ++kt) {
            const float* src = W_hh + row * H + kt * 32 + quad * 8;
            const float4 a = *(const float4*)src;
            const float4 b = *(const float4*)(src + 4);
            bf16x8 f;
            f[0] = f2bf(a.x); f[1] = f2bf(a.y); f[2] = f2bf(a.z); f[3] = f2bf(a.w);
            f[4] = f2bf(b.x); f[5] = f2bf(b.y); f[6] = f2bf(b.z); f[7] = f2bf(b.w);
            afrag[i][kt] = f;
        }
        // acc init = b_hh rows quad*4..quad*4+3 of this tile (C/D: row=quad*4+reg)
        biasf[i] = *(const f32x4*)(b_hh + rt * 16 + quad * 4);
    }

    // --- X_sh[v][g] = b_ih[g] + sum_e W_ih[g][e]*emb[v][e]  (threads 0..383) ---
    if (t < G3) {
        float wi[E];
        #pragma unroll
        for (int e = 0; e < E; ++e) wi[e] = W_ih[t * E + e];
        const float bi = b_ih[t];
        for (int v = 0; v < V; ++v) {
            float a = bi;
            #pragma unroll
            for (int e = 0; e < E; ++e) a = fmaf(wi[e], emb[v * E + e], a);
            X_sh[v * G3 + t] = a;
        }
    }
    if (t < H) hbf_sh[t] = 0;        // h0 = 0
    __syncthreads();

    float h_reg = 0.0f;

    for (int l = 0; l < LSEQ; ++l) {
        // ---- phase A: gh tiles via MFMA (all 8 waves) ----
        // B-frag for k-tile kt: 8 consecutive bf16 of h at k = kt*32 + quad*8,
        // identical for all 16 lanes of a quad row-group (broadcast read).
        bf16x8 bfrag[4];
        #pragma unroll
        for (int kt = 0; kt < 4; ++kt)
            bfrag[kt] = *reinterpret_cast<const bf16x8*>(&hbf_sh[kt * 32 + quad * 8]);

        #pragma unroll
        for (int i = 0; i < 3; ++i) {
            f32x4 acc = biasf[i];
            #pragma unroll
            for (int kt = 0; kt < 4; ++kt)
                acc = __builtin_amdgcn_mfma_f32_16x16x32_bf16(afrag[i][kt], bfrag[kt], acc, 0, 0, 0);
            // D: col = lane&15, row = quad*4 + reg. All cols identical; col 0 writes.
            if (col == 0)
                *reinterpret_cast<f32x4*>(&gh_sh[(3 * w + i) * 16 + quad * 4]) = acc;
        }
        __syncthreads();

        // ---- phase B: gates (threads 0..127) ----
        if (t < H) {
            const int base = tokens[l] * G3;      // uniform scalar load
            const float rr = sigmoidf_(X_sh[base + t]         + gh_sh[t]);
            const float zz = sigmoidf_(X_sh[base + H + t]     + gh_sh[t + H]);
            const float nn = tanhf_(fmaf(rr, gh_sh[t + 2 * H], X_sh[base + 2 * H + t]));
            h_reg = (1.0f - zz) * nn + zz * h_reg;
            const short hb = f2bf(h_reg);
            hbf_sh[t] = hb;
            hiddens[(size_t)l * H + t] = __builtin_bit_cast(__hip_bfloat16, hb);
        }
        __syncthreads();
    }

    // last_hidden = final H elements of d_out (fp32)
    if (t < H) out[out_size - H + t] = h_reg;
}

// ---------------------------------------------------------------------------
// Decode post-pass: logits = hiddens @ W_dec^T + b_dec ; log_softmax ; fp32.
// One sequence row per thread, 128 blocks x 256 threads. W_dec in LDS.
// ---------------------------------------------------------------------------
__global__ void __launch_bounds__(256)
gru_decode(const __hip_bfloat16* __restrict__ hiddens, // [L,H] bf16
           const float* __restrict__ W_dec,            // [O,H]
           const float* __restrict__ b_dec,            // [O]
           float* __restrict__ out)                    // [L,O] fp32
{
    __shared__ float wd[O * H];
    __shared__ float bd[O];
    const int t = threadIdx.x;
    for (int i = t; i < O * H; i += 256) wd[i] = W_dec[i];
    if (t < O) bd[t] = b_dec[t];
    __syncthreads();

    const int row = blockIdx.x * 256 + t;    // grid = L/256
    float logit[O];
    #pragma unroll
    for (int o = 0; o < O; ++o) logit[o] = bd[o];

    const uint4* hp = (const uint4*)(hiddens + (size_t)row * H);
    #pragma unroll
    for (int j = 0; j < H / 8; ++j) {
        const uint4 u = hp[j];
        const float h0 = bflo(u.x), h1 = bfhi(u.x);
        const float h2 = bflo(u.y), h3 = bfhi(u.y);
        const float h4 = bflo(u.z), h5 = bfhi(u.z);
        const float h6 = bflo(u.w), h7 = bfhi(u.w);
        const int c = j * 8;
        #pragma unroll
        for (int o = 0; o < O; ++o) {
            const float* wr = wd + o * H + c;    // uniform addr -> broadcast
            float a = logit[o];
            a = fmaf(wr[0], h0, a); a = fmaf(wr[1], h1, a);
            a = fmaf(wr[2], h2, a); a = fmaf(wr[3], h3, a);
            a = fmaf(wr[4], h4, a); a = fmaf(wr[5], h5, a);
            a = fmaf(wr[6], h6, a); a = fmaf(wr[7], h7, a);
            logit[o] = a;
        }
    }

    float m = logit[0];
    #pragma unroll
    for (int o = 1; o < O; ++o) m = fmaxf(m, logit[o]);
    float s = 0.0f;
    #pragma unroll
    for (int o = 0; o < O; ++o) s += __expf(logit[o] - m);
    const float lse = m + __logf(s);
    #pragma unroll
    for (int o = 0; o < O; ++o)
        out[(size_t)row * O + o] = logit[o] - lse;
}

extern "C" void kernel_launch(void* const* d_in, const int* in_sizes, int n_in,
                              void* d_out, int out_size, void* d_ws, size_t ws_size,
                              hipStream_t stream) {
    const int*   tokens = (const int*)d_in[0];
    const float* emb    = (const float*)d_in[1];
    const float* W_ih   = (const float*)d_in[2];
    const float* W_hh   = (const float*)d_in[3];
    const float* b_ih   = (const float*)d_in[4];
    const float* b_hh   = (const float*)d_in[5];
    const float* W_dec  = (const float*)d_in[6];
    const float* b_dec  = (const float*)d_in[7];
    float* out = (float*)d_out;
    __hip_bfloat16* hiddens = (__hip_bfloat16*)d_ws;   // L*H*2 = 8.4 MB

    gru_scan<<<1, 512, 0, stream>>>(tokens, emb, W_ih, W_hh, b_ih, b_hh,
                                    hiddens, out, out_size);
    gru_decode<<<LSEQ / 256, 256, 0, stream>>>(hiddens, W_dec, b_dec, out);
}

// Round 8
// 16841.232 us; speedup vs baseline: 2.2183x; 1.0158x over previous
//
#include <hip/hip_runtime.h>
#include <hip/hip_bf16.h>

#define H    128
#define E    10
#define V    21
#define O    21
#define LSEQ 32768
#define G3   384            // 3*H

typedef __attribute__((ext_vector_type(8))) short bf16x8;   // 8 bf16 = 4 VGPRs
typedef __attribute__((ext_vector_type(4))) float f32x4;

__device__ __forceinline__ float sigmoidf_(float x) { return 1.0f / (1.0f + __expf(-x)); }
__device__ __forceinline__ float tanhf_(float x)    { return 1.0f - 2.0f / (1.0f + __expf(2.0f * x)); }
__device__ __forceinline__ float bflo(unsigned u) { return __uint_as_float(u << 16); }
__device__ __forceinline__ float bfhi(unsigned u) { return __uint_as_float(u & 0xFFFF0000u); }

__device__ __forceinline__ short f2bf(float f) {
    __hip_bfloat16 h = __float2bfloat16(f);     // RNE
    return __builtin_bit_cast(short, h);
}
// select component c (0..3) of an f32x4 — 3 cndmasks
__device__ __forceinline__ float sel4(f32x4 v, int c) {
    float x = v[0];
    x = (c == 1) ? v[1] : x;
    x = (c == 2) ? v[2] : x;
    x = (c == 3) ? v[3] : x;
    return x;
}

// ---------------------------------------------------------------------------
// GRU scan via MFMA, ONE barrier per step: 512 threads (8 waves).
// Wave w owns tiles {w, w+8, w+16} == rows w*16..w*16+15 of the r-, z- and
// n-gate parts of gh = W_hh·h + b_hh. After its 12 v_mfma_f32_16x16x32_bf16,
// each lane's D regs already hold gh_r/gh_z/gh_n for rows w*16+quad*4+[0..3]
// -> gates computed IN-WAVE (lanes col<4, one row each, D-reg chosen by col).
// No gh LDS round-trip, no second barrier. h double-buffered in LDS (parity)
// so the single step-end barrier is race-free. tokens prefetched 1 step ahead.
// hiddens staged in a 64-step LDS ring, flushed every 64 steps (amortizes the
// vmcnt(0) barrier drain that cost ~250 cyc/step in round 7).
// ---------------------------------------------------------------------------
__global__ void __launch_bounds__(512)
__attribute__((amdgpu_waves_per_eu(2, 2)))
gru_scan(const int*   __restrict__ tokens,
         const float* __restrict__ emb,      // [V,E]
         const float* __restrict__ W_ih,     // [3H,E]
         const float* __restrict__ W_hh,     // [3H,H]
         const float* __restrict__ b_ih,     // [3H]
         const float* __restrict__ b_hh,     // [3H]
         __hip_bfloat16* __restrict__ hiddens,  // ws [L,H] bf16
         float* __restrict__ out,            // fp32 d_out
         int out_size)
{
    __shared__ __align__(16) float X4_sh[V * H * 4];  // [v][row][xr,xz,xn,pad] 43 KB
    __shared__ __align__(16) short hbuf[2][H];        // h (bf16), double-buffered
    __shared__ __align__(16) short ring[64][H];       // 16 KB hiddens staging

    const int t    = threadIdx.x;     // 0..511
    const int w    = t >> 6;          // wave 0..7
    const int lane = t & 63;
    const int quad = lane >> 4;       // 0..3
    const int col  = lane & 15;       // MFMA m / n index
    const int grow = w * 16 + quad * 4 + col;   // gate row (valid when col<4)

    // --- A-fragments: wave w, gate part p -> tile T = w + 8p, rows T*16+col ---
    // A[m][k]: m = lane&15, k = quad*8 + j
    bf16x8 afrag[3][4];
    f32x4  biasf[3];
    #pragma unroll
    for (int p = 0; p < 3; ++p) {
        const int T   = w + 8 * p;
        const int row = T * 16 + col;
        #pragma unroll
        for (int kt = 0; kt < 4; ++kt) {
            const float* src = W_hh + row * H + kt * 32 + quad * 8;
            const float4 a = *(const float4*)src;
            const float4 b = *(const float4*)(src + 4);
            bf16x8 f;
            f[0] = f2bf(a.x); f[1] = f2bf(a.y); f[2] = f2bf(a.z); f[3] = f2bf(a.w);
            f[4] = f2bf(b.x); f[5] = f2bf(b.y); f[6] = f2bf(b.z); f[7] = f2bf(b.w);
            afrag[p][kt] = f;
        }
        biasf[p] = *(const f32x4*)(b_hh + T * 16 + quad * 4);   // D row = quad*4+reg
    }

    // --- X4_sh[v][r] = (xr, xz, xn, 0) with b_ih folded in ---
    for (int idx = t; idx < V * H; idx += 512) {
        const int v = idx >> 7, r = idx & 127;
        float s0 = b_ih[r], s1 = b_ih[r + 128], s2 = b_ih[r + 256];
        #pragma unroll
        for (int e = 0; e < E; ++e) {
            const float ev = emb[v * E + e];
            s0 = fmaf(W_ih[r * E + e],         ev, s0);
            s1 = fmaf(W_ih[(r + 128) * E + e], ev, s1);
            s2 = fmaf(W_ih[(r + 256) * E + e], ev, s2);
        }
        f32x4 xr = {s0, s1, s2, 0.0f};
        *reinterpret_cast<f32x4*>(&X4_sh[idx * 4]) = xr;
    }
    if (t < H) { hbuf[0][t] = 0; hbuf[1][t] = 0; }
    __syncthreads();

    float h_reg = 0.0f;
    int tok = tokens[0];

    for (int l = 0; l < LSEQ; ++l) {
        const int par = l & 1;
        const int tok_next = tokens[(l + 1 < LSEQ) ? (l + 1) : l];  // prefetch

        // B-frags: 8 consecutive bf16 of h at k = kt*32 + quad*8 (broadcast)
        bf16x8 bfrag[4];
        #pragma unroll
        for (int kt = 0; kt < 4; ++kt)
            bfrag[kt] = *reinterpret_cast<const bf16x8*>(&hbuf[par][kt * 32 + quad * 8]);

        // X for this lane's gate row — depends only on prefetched tok,
        // issued before the MFMAs so its latency overlaps the chain.
        f32x4 xv;
        if (col < 4)
            xv = *reinterpret_cast<const f32x4*>(&X4_sh[(tok * H + grow) * 4]);

        f32x4 acc[3];
        #pragma unroll
        for (int p = 0; p < 3; ++p) {
            acc[p] = biasf[p];
            #pragma unroll
            for (int kt = 0; kt < 4; ++kt)
                acc[p] = __builtin_amdgcn_mfma_f32_16x16x32_bf16(afrag[p][kt], bfrag[kt], acc[p], 0, 0, 0);
        }

        if (col < 4) {
            const float gr = sel4(acc[0], col);
            const float gz = sel4(acc[1], col);
            const float gn = sel4(acc[2], col);
            const float rr = sigmoidf_(xv.x + gr);
            const float zz = sigmoidf_(xv.y + gz);
            const float nn = tanhf_(fmaf(rr, gn, xv.z));
            h_reg = (1.0f - zz) * nn + zz * h_reg;
            const short hb = f2bf(h_reg);
            hbuf[par ^ 1][grow] = hb;
            ring[l & 63][grow]  = hb;
        }
        __syncthreads();

        if ((l & 63) == 63) {    // flush ring -> hiddens (uniform branch)
            const uint4* rsrc = (const uint4*)&ring[0][0];   // 1024 uint4
            uint4* dst = (uint4*)(hiddens + (size_t)(l - 63) * H);
            dst[t]       = rsrc[t];
            dst[t + 512] = rsrc[t + 512];
            __syncthreads();     // ring slot 0 is rewritten next step
        }
        tok = tok_next;
    }

    // last_hidden = final H elements of d_out (fp32)
    if (col < 4) out[out_size - H + grow] = h_reg;
}

// ---------------------------------------------------------------------------
// Decode post-pass: logits = hiddens @ W_dec^T + b_dec ; log_softmax ; fp32.
// One sequence row per thread, 128 blocks x 256 threads. W_dec in LDS.
// ---------------------------------------------------------------------------
__global__ void __launch_bounds__(256)
gru_decode(const __hip_bfloat16* __restrict__ hiddens, // [L,H] bf16
           const float* __restrict__ W_dec,            // [O,H]
           const float* __restrict__ b_dec,            // [O]
           float* __restrict__ out)                    // [L,O] fp32
{
    __shared__ float wd[O * H];
    __shared__ float bd[O];
    const int t = threadIdx.x;
    for (int i = t; i < O * H; i += 256) wd[i] = W_dec[i];
    if (t < O) bd[t] = b_dec[t];
    __syncthreads();

    const int row = blockIdx.x * 256 + t;    // grid = L/256
    float logit[O];
    #pragma unroll
    for (int o = 0; o < O; ++o) logit[o] = bd[o];

    const uint4* hp = (const uint4*)(hiddens + (size_t)row * H);
    #pragma unroll
    for (int j = 0; j < H / 8; ++j) {
        const uint4 u = hp[j];
        const float h0 = bflo(u.x), h1 = bfhi(u.x);
        const float h2 = bflo(u.y), h3 = bfhi(u.y);
        const float h4 = bflo(u.z), h5 = bfhi(u.z);
        const float h6 = bflo(u.w), h7 = bfhi(u.w);
        const int c = j * 8;
        #pragma unroll
        for (int o = 0; o < O; ++o) {
            const float* wr = wd + o * H + c;    // uniform addr -> broadcast
            float a = logit[o];
            a = fmaf(wr[0], h0, a); a = fmaf(wr[1], h1, a);
            a = fmaf(wr[2], h2, a); a = fmaf(wr[3], h3, a);
            a = fmaf(wr[4], h4, a); a = fmaf(wr[5], h5, a);
            a = fmaf(wr[6], h6, a); a = fmaf(wr[7], h7, a);
            logit[o] = a;
        }
    }

    float m = logit[0];
    #pragma unroll
    for (int o = 1; o < O; ++o) m = fmaxf(m, logit[o]);
    float s = 0.0f;
    #pragma unroll
    for (int o = 0; o < O; ++o) s += __expf(logit[o] - m);
    const float lse = m + __logf(s);
    #pragma unroll
    for (int o = 0; o < O; ++o)
        out[(size_t)row * O + o] = logit[o] - lse;
}

extern "C" void kernel_launch(void* const* d_in, const int* in_sizes, int n_in,
                              void* d_out, int out_size, void* d_ws, size_t ws_size,
                              hipStream_t stream) {
    const int*   tokens = (const int*)d_in[0];
    const float* emb    = (const float*)d_in[1];
    const float* W_ih   = (const float*)d_in[2];
    const float* W_hh   = (const float*)d_in[3];
    const float* b_ih   = (const float*)d_in[4];
    const float* b_hh   = (const float*)d_in[5];
    const float* W_dec  = (const float*)d_in[6];
    const float* b_dec  = (const float*)d_in[7];
    float* out = (float*)d_out;
    __hip_bfloat16* hiddens = (__hip_bfloat16*)d_ws;   // L*H*2 = 8.4 MB

    gru_scan<<<1, 512, 0, stream>>>(tokens, emb, W_ih, W_hh, b_ih, b_hh,
                                    hiddens, out, out_size);
    gru_decode<<<LSEQ / 256, 256, 0, stream>>>(hiddens, W_dec, b_dec, out);
}